// Round 11
// baseline (569.499 us; speedup 1.0000x reference)
//
#include <hip/hip_runtime.h>
#include <hip/hip_fp16.h>

#define NN 20000
#define EE 600000

typedef unsigned short u16;
typedef unsigned char u8;
typedef unsigned int u32;
typedef float f32x4 __attribute__((ext_vector_type(4)));
typedef u32 u32x4 __attribute__((ext_vector_type(4)));
typedef u32 u32x2 __attribute__((ext_vector_type(2)));

__device__ __forceinline__ u16 f2bf(float f){
  u32 u = __float_as_uint(f);
  return (u16)((u + 0x7fffu + ((u>>16)&1u))>>16);
}
__device__ __forceinline__ float bf2f(u16 h){ return __uint_as_float(((u32)h)<<16); }

// e5m2 (bf8) = top byte of binary16. encode: f32->f16 RNE, then RNE to 8 bits.
__device__ __forceinline__ u8 f2bf8(float v){
  __half h = __float2half(v);
  u16 b = *(u16*)&h;
  return (u8)((b + 0x7Fu + ((b>>8)&1u)) >> 8);
}
__device__ __forceinline__ float bf82f(u32 byte){
  __half_raw r; r.x = (u16)(byte << 8);
  return __half2float(__half(r));
}

// jax.nn.gelu default (approximate=True, tanh form)
__device__ __forceinline__ float gelu_f(float x){
  float u = 0.7978845608028654f*(x + 0.044715f*x*x*x);
  float e = __expf(2.0f*u);
  return 0.5f*x*(2.0f - 2.0f/(e+1.0f));   // 0.5x(1+tanh(u)), overflow-safe
}

// ---------------------------------------------------------------------------
// Fused prologue: ONE dispatch for all mutually-independent prep work.
//   blocks [0,1536):   6 weight transposes (fp32 -> bf16 [N][Kpad])
//   [1536,1849):       out-init + bqk concat
//   [1849,6849):       LayerNorm x2 (zatt + xf[0:512])
//   [6849,9193):       edge histogram (deg zeroed by prior memset)
// ---------------------------------------------------------------------------
struct WttDesc { const float* W; u16* WT; int K, Nn, Kpad; };
struct WttPack { WttDesc d[6]; };

#define B_WTT  1536
#define B_PREP 313
#define B_LN2  5000
#define B_HIST 2344

__global__ __launch_bounds__(256) void misc_kernel(
    WttPack p,
    float* __restrict__ out, const float* __restrict__ beO, const float* __restrict__ bfO,
    float* __restrict__ bqk, const float* __restrict__ bq, const float* __restrict__ bk,
    const float* __restrict__ x,
    const float* __restrict__ ga, const float* __restrict__ ba,
    const float* __restrict__ gm, const float* __restrict__ bm,
    u16* __restrict__ za, u16* __restrict__ xf,
    const int* __restrict__ ei, int* __restrict__ deg)
{
  __shared__ u16 tile[64][65];
  const int b = blockIdx.x;
  const int tid = threadIdx.x;
  if(b < B_WTT){
    const WttDesc dd = p.d[b >> 8];
    const int r8 = b & 255;
    const int k0 = (r8 & 15) << 6, n0 = (r8 >> 4) << 6;
    if(k0 >= dd.Kpad || n0 >= dd.Nn) return;
    const int tx = tid & 63, ty = tid >> 6;
#pragma unroll
    for(int i=0;i<16;i++){
      int r = (i<<2) + ty;
      int gk = k0 + r;
      float v = (gk < dd.K) ? dd.W[(size_t)gk*dd.Nn + n0 + tx] : 0.f;
      tile[r][tx] = f2bf(v);
    }
    __syncthreads();
#pragma unroll
    for(int i=0;i<16;i++){
      int r = (i<<2) + ty;
      dd.WT[(size_t)(n0 + r)*dd.Kpad + k0 + tx] = tile[tx][r];
    }
  } else if(b < B_WTT + B_PREP){
    int idx = (b - B_WTT)*256 + tid;
    if(idx < NN) out[idx] = beO[0];
    else if(idx < NN*4) out[idx] = bfO[(idx - NN) % 3];
    if(idx < 512) bqk[idx] = bq[idx];
    else if(idx < 1024) bqk[idx] = bk[idx-512];
  } else if(b < B_WTT + B_PREP + B_LN2){
    int row = ((b - B_WTT - B_PREP)<<2) + (tid>>6);
    int lane = tid & 63;
    if(row >= NN) return;
    const float* xp = x + ((size_t)row<<9) + (lane<<3);
    f32x4 v0 = *(const f32x4*)xp;
    f32x4 v1 = *(const f32x4*)(xp+4);
    float vals[8] = {v0[0],v0[1],v0[2],v0[3],v1[0],v1[1],v1[2],v1[3]};
    float s=0.f, qs=0.f;
#pragma unroll
    for(int i=0;i<8;i++){ s += vals[i]; qs = fmaf(vals[i],vals[i],qs); }
#pragma unroll
    for(int o=1;o<64;o<<=1){ s += __shfl_xor(s,o); qs += __shfl_xor(qs,o); }
    float mean = s*(1.f/512.f);
    float var  = qs*(1.f/512.f) - mean*mean;
    float rstd = rsqrtf(var + 1e-5f);
    int c0 = lane<<3;
#pragma unroll
    for(int i=0;i<8;i++){
      float zn = (vals[i]-mean)*rstd;
      za[((size_t)row<<9)+c0+i] = f2bf(fmaf(zn, ga[c0+i], ba[c0+i]));
      xf[(size_t)row*576+c0+i]  = f2bf(fmaf(zn, gm[c0+i], bm[c0+i]));
    }
  } else {
    int e = (b - B_WTT - B_PREP - B_LN2)*256 + tid;
    if(e < EE) atomicAdd(&deg[ei[e]], 1);
  }
}

// ---------------------------------------------------------------------------
// GEMM device body, modes 0/1 (r5-verified config: 128x128x64 tiles,
// MFMA 16x16x32, XOR-swizzled LDS, global_load_lds w=16, single-buffered,
// XCD-stripe mapping from virtual block id vb; N-tiles fixed at 8).
// mode 0: QK proj -> q bf16 (stride 512) + k bf8.  mode 1: gelu -> Cb (ldc).
// ---------------------------------------------------------------------------
struct GemmP {
  const u16* A; const u16* B; const float* bias;
  u16* Cb; u8* k8; int M, K, lda, ldc, mode;
};

__device__ __forceinline__ void gemm01(const GemmP g, int vb)
{
  __shared__ u16 As[128*64];
  __shared__ u16 Bs[128*64];
  const int xcd = vb & 7, loc = vb >> 3;
  const int tileM = (((loc>>3)<<3) + xcd) << 7;
  const int tileN = (loc & 7) << 7;
  if(tileM >= g.M) return;
  const int tid  = threadIdx.x;
  const int wave = tid>>6, lane = tid&63;
  const int quad = lane>>4, l15 = lane&15;
  const int mhalf = (wave>>1)<<6, nhalf = (wave&1)<<6;
  f32x4 acc[4][4] = {};

  for(int k0=0; k0<g.K; k0+=64){
#pragma unroll
    for(int j=0;j<4;j++){
      const int c   = (((wave<<2)+j)<<6) + lane;
      const int row = c>>3;
      const int cc  = (c&7) ^ (row&7);
      int gr = tileM + row; gr = (gr < g.M) ? gr : (g.M-1);
      const u16* gp = g.A + (size_t)gr*g.lda + (size_t)(k0 + (cc<<3));
      __builtin_amdgcn_global_load_lds(
        (const __attribute__((address_space(1))) u32*)gp,
        (__attribute__((address_space(3))) u32*)(&As[((wave<<2)+j)<<9]),
        16, 0, 0);
    }
#pragma unroll
    for(int j=0;j<4;j++){
      const int c   = (((wave<<2)+j)<<6) + lane;
      const int row = c>>3;
      const int cc  = (c&7) ^ (row&7);
      const u16* gp = g.B + (size_t)(tileN + row)*g.K + (size_t)(k0 + (cc<<3));
      __builtin_amdgcn_global_load_lds(
        (const __attribute__((address_space(1))) u32*)gp,
        (__attribute__((address_space(3))) u32*)(&Bs[((wave<<2)+j)<<9]),
        16, 0, 0);
    }
    __syncthreads();
#pragma unroll
    for(int ks=0;ks<2;ks++){
      const int ccol = (ks<<2) + quad;
      u32x4 af[4], bfr[4];
#pragma unroll
      for(int mi=0;mi<4;mi++){
        const int row = mhalf + (mi<<4) + l15;
        af[mi] = *(const u32x4*)&As[((row<<3) + (ccol ^ (row&7)))<<3];
      }
#pragma unroll
      for(int ni=0;ni<4;ni++){
        const int row = nhalf + (ni<<4) + l15;
        bfr[ni] = *(const u32x4*)&Bs[((row<<3) + (ccol ^ (row&7)))<<3];
      }
#pragma unroll
      for(int mi=0;mi<4;mi++)
#pragma unroll
        for(int ni=0;ni<4;ni++)
          asm("v_mfma_f32_16x16x32_bf16 %0, %1, %2, %0"
              : "+v"(acc[mi][ni]) : "v"(af[mi]), "v"(bfr[ni]));
    }
    __syncthreads();
  }

#pragma unroll
  for(int mi=0;mi<4;mi++){
#pragma unroll
    for(int reg=0;reg<4;reg++){
      const int gr = tileM + mhalf + (mi<<4) + (quad<<2) + reg;
      if(gr < g.M){
#pragma unroll
        for(int ni=0;ni<4;ni++){
          const int gc = tileN + nhalf + (ni<<4) + l15;
          float v = acc[mi][ni][reg] + g.bias[gc];
          if(g.mode == 0){
            if(gc < 512) g.Cb[(size_t)gr*512 + gc] = f2bf(v);
            else         g.k8[(size_t)gr*512 + gc - 512] = f2bf8(v);
          } else {
            g.Cb[(size_t)gr*g.ldc + gc] = f2bf(gelu_f(v));
          }
        }
      }
    }
  }
}

// ---------------------------------------------------------------------------
// node_att device body: one wave per node; q bf16 regs, k bf8 gather,
// softmax w/o max-subtraction, register accumulators, att-pos -> xf[512:536].
// ---------------------------------------------------------------------------
__device__ __forceinline__ void node_att_body(
    int vb, const u16* __restrict__ qd, const u8* __restrict__ k8,
    const int* __restrict__ rowptr, const int* __restrict__ cols,
    const float* __restrict__ abs_, const float* __restrict__ pos,
    u16* __restrict__ xf)
{
  const int node = (vb<<2) + (threadIdx.x>>6);
  const int lane = threadIdx.x & 63;
  if(node >= NN) return;
  const int h = lane>>3, sub = lane&7;
  const u32x4 qv = *(const u32x4*)(qd + ((size_t)node<<9) + (lane<<3));
  float qf[8];
#pragma unroll
  for(int i=0;i<4;i++){
    qf[2*i]   = __uint_as_float(qv[i]<<16);
    qf[2*i+1] = __uint_as_float(qv[i]&0xffff0000u);
  }
  const float posn = (sub<3) ? pos[node*3 + sub] : 0.f;
  const int j1 = rowptr[node+1];
  float den = 0.f, nm = 0.f;

  int j = rowptr[node];
  for(; j+7 < j1; j += 8){
    int c[8]; float abv[8], pv[8]; u32x2 kw[8];
#pragma unroll
    for(int t=0;t<8;t++){ c[t] = cols[j+t]; abv[t] = abs_[j+t]; }
#pragma unroll
    for(int t=0;t<8;t++){
      kw[t] = *(const u32x2*)(k8 + ((size_t)c[t]<<9) + (lane<<3));
      pv[t] = (sub<3) ? pos[c[t]*3+sub] : 0.f;
    }
#pragma unroll
    for(int t=0;t<8;t++){
      float s = 0.f;
#pragma unroll
      for(int i=0;i<8;i++){
        u32 byte = (kw[t][i>>2] >> ((i&3)<<3)) & 0xFFu;
        s = fmaf(qf[i], bf82f(byte), s);
      }
      s += __shfl_xor(s,1); s += __shfl_xor(s,2); s += __shfl_xor(s,4);
      float p = __expf(fmaf(s, 0.125f, abv[t]));
      den += p;
      nm = fmaf(p, pv[t], nm);
    }
  }
  for(; j < j1; j++){
    int c0 = cols[j];
    u32x2 kw0 = *(const u32x2*)(k8 + ((size_t)c0<<9) + (lane<<3));
    float pv0 = (sub<3) ? pos[c0*3+sub] : 0.f;
    float s0=0.f;
#pragma unroll
    for(int i=0;i<8;i++){
      u32 byte = (kw0[i>>2] >> ((i&3)<<3)) & 0xFFu;
      s0 = fmaf(qf[i], bf82f(byte), s0);
    }
    s0 += __shfl_xor(s0,1); s0 += __shfl_xor(s0,2); s0 += __shfl_xor(s0,4);
    float p0 = __expf(fmaf(s0, 0.125f, abs_[j]));
    den += p0;
    nm = fmaf(p0, pv0, nm);
  }

  u16* xp = xf + (size_t)node*576;
  if(sub < 3){
    float a = (den > 0.f) ? nm/den : 0.f;
    xp[512 + h*3 + sub] = f2bf(a - posn);
  } else {
    xp[536 + h*5 + (sub-3)] = 0;   // pad cols 536..575
  }
}

// ---------------------------------------------------------------------------
// mega1: blocks [0,1280) = QK-projection GEMM (mode 0);
//        blocks [1280,3624) = edge scatter (counting-sort phase 3).
// Independent: scatter needs scan, GEMM needs misc. Co-scheduled (m114).
// ---------------------------------------------------------------------------
__global__ __launch_bounds__(256) void mega1_kernel(
    GemmP g, const int* __restrict__ ei, const float* __restrict__ ab,
    int* __restrict__ cursor, int* __restrict__ cols, float* __restrict__ abs_)
{
  const int b = blockIdx.x;
  if(b < 1280){
    gemm01(g, b);
  } else {
    int e = (b - 1280)*256 + threadIdx.x;
    if(e >= EE) return;
    int r = ei[e];
    int p = atomicAdd(&cursor[r], 1);
    cols[p] = ei[EE + e];
    abs_[p] = ab[e];
  }
}

// ---------------------------------------------------------------------------
// mega2: blocks [0,1280) = energy in-proj GEMM (K=512, reads xf[:,0:512]);
//        blocks [1280,6280) = node_att (writes xf[:,512:576]). Disjoint data.
// ---------------------------------------------------------------------------
__global__ __launch_bounds__(256) void mega2_kernel(
    GemmP g, const u16* __restrict__ qd, const u8* __restrict__ k8,
    const int* __restrict__ rowptr, const int* __restrict__ cols,
    const float* __restrict__ abs_, const float* __restrict__ pos,
    u16* __restrict__ xf)
{
  const int b = blockIdx.x;
  if(b < 1280) gemm01(g, b);
  else         node_att_body(b - 1280, qd, k8, rowptr, cols, abs_, pos, xf);
}

__global__ __launch_bounds__(256) void gemm01_kernel(GemmP g)
{
  gemm01(g, blockIdx.x);
}

// ---------------------------------------------------------------------------
// MERGED hidden GEMM + fused residual/out-proj epilogue (r9-verified):
// XCDs 0-3 energy head, XCDs 4-7 forces head; per-XCD B = 2 MB (L2-fit).
// ---------------------------------------------------------------------------
__global__ __launch_bounds__(256) void gemm_hidden(
    const u16* __restrict__ A, const u16* __restrict__ B,
    const float* __restrict__ bias, const u16* __restrict__ resid,
    const float* __restrict__ wout, float* __restrict__ outp,
    const u16* __restrict__ B2, const float* __restrict__ bias2,
    const float* __restrict__ wout2, float* __restrict__ outp2,
    int M, int K, int lda, int ldr)
{
  __shared__ u16 As[128*64];
  __shared__ u16 Bs[128*64];
  const int gx = gridDim.x;
  const int b  = blockIdx.y*gx + blockIdx.x;
  const int xcd = b & 7, loc = b >> 3;
  const int half = xcd >> 2;
  const int mt = ((loc>>3)<<2) + (xcd & 3);
  const int tileM = mt << 7;
  const int tileN = (loc & 7) << 7;
  const u16* Ab = half ? (A + 1024) : A;
  const u16* Bp = half ? B2 : B;
  const float* bp = half ? bias2 : bias;
  if(tileM >= M) return;
  const int tid  = threadIdx.x;
  const int wave = tid>>6, lane = tid&63;
  const int quad = lane>>4, l15 = lane&15;
  const int mhalf = (wave>>1)<<6, nhalf = (wave&1)<<6;
  f32x4 acc[4][4] = {};

  for(int k0=0; k0<K; k0+=64){
#pragma unroll
    for(int j=0;j<4;j++){
      const int c   = (((wave<<2)+j)<<6) + lane;
      const int row = c>>3;
      const int cc  = (c&7) ^ (row&7);
      int gr = tileM + row; gr = (gr < M) ? gr : (M-1);
      const u16* gp = Ab + (size_t)gr*lda + (size_t)(k0 + (cc<<3));
      __builtin_amdgcn_global_load_lds(
        (const __attribute__((address_space(1))) u32*)gp,
        (__attribute__((address_space(3))) u32*)(&As[((wave<<2)+j)<<9]),
        16, 0, 0);
    }
#pragma unroll
    for(int j=0;j<4;j++){
      const int c   = (((wave<<2)+j)<<6) + lane;
      const int row = c>>3;
      const int cc  = (c&7) ^ (row&7);
      const u16* gp = Bp + (size_t)(tileN + row)*K + (size_t)(k0 + (cc<<3));
      __builtin_amdgcn_global_load_lds(
        (const __attribute__((address_space(1))) u32*)gp,
        (__attribute__((address_space(3))) u32*)(&Bs[((wave<<2)+j)<<9]),
        16, 0, 0);
    }
    __syncthreads();
#pragma unroll
    for(int ks=0;ks<2;ks++){
      const int ccol = (ks<<2) + quad;
      u32x4 af[4], bfr[4];
#pragma unroll
      for(int mi=0;mi<4;mi++){
        const int row = mhalf + (mi<<4) + l15;
        af[mi] = *(const u32x4*)&As[((row<<3) + (ccol ^ (row&7)))<<3];
      }
#pragma unroll
      for(int ni=0;ni<4;ni++){
        const int row = nhalf + (ni<<4) + l15;
        bfr[ni] = *(const u32x4*)&Bs[((row<<3) + (ccol ^ (row&7)))<<3];
      }
#pragma unroll
      for(int mi=0;mi<4;mi++)
#pragma unroll
        for(int ni=0;ni<4;ni++)
          asm("v_mfma_f32_16x16x32_bf16 %0, %1, %2, %0"
              : "+v"(acc[mi][ni]) : "v"(af[mi]), "v"(bfr[ni]));
    }
    __syncthreads();
  }

  if(!half){
    float wv[4], bv[4];
#pragma unroll
    for(int ni=0;ni<4;ni++){
      int gc = tileN + nhalf + (ni<<4) + l15;
      wv[ni] = wout[gc]; bv[ni] = bp[gc];
    }
#pragma unroll
    for(int mi=0;mi<4;mi++){
#pragma unroll
      for(int reg=0;reg<4;reg++){
        const int gr = tileM + mhalf + (mi<<4) + (quad<<2) + reg;
        if(gr < M){
          float vs = 0.f;
#pragma unroll
          for(int ni=0;ni<4;ni++){
            const int gc = tileN + nhalf + (ni<<4) + l15;
            float v = gelu_f(acc[mi][ni][reg] + bv[ni])
                    + bf2f(resid[(size_t)gr*ldr + gc]);
            vs = fmaf(v, wv[ni], vs);
          }
          vs += __shfl_xor(vs,1); vs += __shfl_xor(vs,2);
          vs += __shfl_xor(vs,4); vs += __shfl_xor(vs,8);
          if(l15 == 0) atomicAdd(&outp[gr], vs);
        }
      }
    }
  } else {
    float wv0[4], wv1[4], wv2[4], bv[4];
#pragma unroll
    for(int ni=0;ni<4;ni++){
      int gc = tileN + nhalf + (ni<<4) + l15;
      wv0[ni] = wout2[gc*3+0]; wv1[ni] = wout2[gc*3+1]; wv2[ni] = wout2[gc*3+2];
      bv[ni] = bp[gc];
    }
#pragma unroll
    for(int mi=0;mi<4;mi++){
#pragma unroll
      for(int reg=0;reg<4;reg++){
        const int gr = tileM + mhalf + (mi<<4) + (quad<<2) + reg;
        if(gr < M){
          float s0=0.f, s1=0.f, s2=0.f;
#pragma unroll
          for(int ni=0;ni<4;ni++){
            const int gc = tileN + nhalf + (ni<<4) + l15;
            float v = gelu_f(acc[mi][ni][reg] + bv[ni])
                    + bf2f(resid[(size_t)gr*ldr + 1024 + gc]);
            s0 = fmaf(v, wv0[ni], s0);
            s1 = fmaf(v, wv1[ni], s1);
            s2 = fmaf(v, wv2[ni], s2);
          }
          s0 += __shfl_xor(s0,1); s0 += __shfl_xor(s0,2); s0 += __shfl_xor(s0,4); s0 += __shfl_xor(s0,8);
          s1 += __shfl_xor(s1,1); s1 += __shfl_xor(s1,2); s1 += __shfl_xor(s1,4); s1 += __shfl_xor(s1,8);
          s2 += __shfl_xor(s2,1); s2 += __shfl_xor(s2,2); s2 += __shfl_xor(s2,4); s2 += __shfl_xor(s2,8);
          if(l15 == 0){
            atomicAdd(&outp2[(size_t)gr*3+0], s0);
            atomicAdd(&outp2[(size_t)gr*3+1], s1);
            atomicAdd(&outp2[(size_t)gr*3+2], s2);
          }
        }
      }
    }
  }
}

// single-block exclusive scan, shuffle-based (2 barriers per 1024 chunk)
__global__ __launch_bounds__(1024) void scan_kernel(
    const int* __restrict__ deg, int* __restrict__ rowptr,
    int* __restrict__ cursor, int N)
{
  __shared__ int wsum[16];
  __shared__ int carry_s;
  const int tid = threadIdx.x, lane = tid & 63, wid = tid >> 6;
  if(tid == 0) carry_s = 0;
  __syncthreads();
  for(int base = 0; base < N; base += 1024){
    int idx = base + tid;
    int v = (idx < N) ? deg[idx] : 0;
    int s = v;
#pragma unroll
    for(int o=1;o<64;o<<=1){ int t = __shfl_up(s,o); if(lane>=o) s += t; }
    if(lane==63) wsum[wid] = s;
    __syncthreads();
    if(wid==0 && lane<16){
      int ws = wsum[lane];
      int t = ws;
#pragma unroll
      for(int o=1;o<16;o<<=1){ int u = __shfl_up(t,o); if(lane>=o) t += u; }
      wsum[lane] = t - ws;
    }
    __syncthreads();
    int ex = s - v + wsum[wid] + carry_s;
    if(idx < N){ rowptr[idx] = ex; cursor[idx] = ex; }
    __syncthreads();
    if(tid == 1023) carry_s += wsum[15] + s;
  }
  __syncthreads();
  if(tid == 0) rowptr[N] = carry_s;
}

// ---------------------------------------------------------------------------
extern "C" void kernel_launch(void* const* d_in, const int* in_sizes, int n_in,
                              void* d_out, int out_size, void* d_ws, size_t ws_size,
                              hipStream_t stream)
{
  (void)in_sizes; (void)n_in; (void)out_size; (void)ws_size;
  const float* x    = (const float*)d_in[0];
  const int*   ei   = (const int*)d_in[1];
  const float* ab   = (const float*)d_in[2];
  const float* pos  = (const float*)d_in[3];
  const float* g_att= (const float*)d_in[5];
  const float* b_att= (const float*)d_in[6];
  const float* g_mlp= (const float*)d_in[7];
  const float* b_mlp= (const float*)d_in[8];
  const float* Wq   = (const float*)d_in[9];  const float* bq  = (const float*)d_in[10];
  const float* Wk   = (const float*)d_in[11]; const float* bk  = (const float*)d_in[12];
  const float* WeI  = (const float*)d_in[13]; const float* beI = (const float*)d_in[14];
  const float* WeH  = (const float*)d_in[15]; const float* beH = (const float*)d_in[16];
  const float* WeO  = (const float*)d_in[17]; const float* beO = (const float*)d_in[18];
  const float* WfI  = (const float*)d_in[19]; const float* bfI = (const float*)d_in[20];
  const float* WfH  = (const float*)d_in[21]; const float* bfH = (const float*)d_in[22];
  const float* WfO  = (const float*)d_in[23]; const float* bfO = (const float*)d_in[24];

  char* w = (char*)d_ws;
  size_t off = 0;
  auto alloc = [&](size_t bytes) -> void* {
    void* p = w + off; off += (bytes + 255) & ~(size_t)255; return p;
  };
  u16* zatt  = (u16*)alloc((size_t)NN*512*2);
  u16* qd    = (u16*)alloc((size_t)NN*512*2);    // q bf16
  u8*  k8    = (u8*) alloc((size_t)NN*512);      // k bf8 (e5m2)
  u16* xf    = (u16*)alloc((size_t)NN*576*2);    // [z_mlp(512)|att(24)|0(40)]
  u16* h1cat = (u16*)alloc((size_t)NN*2048*2);   // [h1_energy(1024)|h1_forces(1024)]
  u16* wqkT  = (u16*)alloc((size_t)1024*512*2);
  u16* weIT  = (u16*)alloc((size_t)1024*512*2);  // K=512, no pad
  u16* wfIT  = (u16*)alloc((size_t)1024*576*2);  // K=576 (536 padded)
  u16* weHT  = (u16*)alloc((size_t)1024*1024*2);
  u16* wfHT  = (u16*)alloc((size_t)1024*1024*2);
  float* bqk    = (float*)alloc((size_t)1024*4);
  int*   deg    = (int*)alloc((size_t)NN*4);
  int*   rowptr = (int*)alloc((size_t)(NN+1)*4);
  int*   cursor = (int*)alloc((size_t)NN*4);
  int*   cols   = (int*)alloc((size_t)EE*4);
  float* absrt  = (float*)alloc((size_t)EE*4);

  hipMemsetAsync(deg, 0, (size_t)NN*4, stream);

  // fused prologue: 6 weight transposes + out/bias init + LN x2 + histogram
  WttPack pk;
  pk.d[0] = { Wq,  wqkT, 512,  512,  512 };
  pk.d[1] = { Wk,  wqkT + 512*512, 512, 512, 512 };
  pk.d[2] = { WeI, weIT, 512,  1024, 512 };
  pk.d[3] = { WfI, wfIT, 536,  1024, 576 };
  pk.d[4] = { WeH, weHT, 1024, 1024, 1024 };
  pk.d[5] = { WfH, wfHT, 1024, 1024, 1024 };
  misc_kernel<<<dim3(B_WTT+B_PREP+B_LN2+B_HIST),256,0,stream>>>(
      pk, (float*)d_out, beO, bfO, bqk, bq, bk,
      x, g_att, b_att, g_mlp, b_mlp, zatt, xf, ei, deg);

  scan_kernel<<<1,1024,0,stream>>>(deg, rowptr, cursor, NN);

  // mega1: QK projection GEMM (mode 0) co-scheduled with edge scatter
  GemmP gqk = { zatt, wqkT, bqk, qd, k8, NN, 512, 512, 512, 0 };
  mega1_kernel<<<dim3(1280 + 2344),256,0,stream>>>(gqk, ei, ab, cursor, cols, absrt);

  // mega2: energy in-proj GEMM (K=512, xf cols 0:512) co-scheduled with node_att
  GemmP gie = { xf, weIT, beI, h1cat, nullptr, NN, 512, 576, 2048, 1 };
  mega2_kernel<<<dim3(1280 + 5000),256,0,stream>>>(gie, qd, k8, rowptr, cols, absrt, pos, xf);

  // forces in-proj GEMM (K=576, includes att columns)
  GemmP gif = { xf, wfIT, bfI, h1cat + 1024, nullptr, NN, 576, 576, 2048, 1 };
  gemm01_kernel<<<dim3(1280),256,0,stream>>>(gif);

  // merged hidden GEMM: XCDs 0-3 energy, XCDs 4-7 forces
  gemm_hidden<<<dim3(8, 320),256,0,stream>>>(h1cat, weHT, beH, h1cat,
                                             WeO, (float*)d_out,
                                             wfHT, bfH, WfO, (float*)d_out + NN,
                                             NN, 1024, 2048, 2048);
}

// Round 12
// 507.688 us; speedup vs baseline: 1.1217x; 1.1217x over previous
//
#include <hip/hip_runtime.h>
#include <hip/hip_fp16.h>

#define NN 20000
#define EE 600000

typedef unsigned short u16;
typedef unsigned char u8;
typedef unsigned int u32;
typedef float f32x4 __attribute__((ext_vector_type(4)));
typedef u32 u32x4 __attribute__((ext_vector_type(4)));
typedef u32 u32x2 __attribute__((ext_vector_type(2)));

__device__ __forceinline__ u16 f2bf(float f){
  u32 u = __float_as_uint(f);
  return (u16)((u + 0x7fffu + ((u>>16)&1u))>>16);
}
__device__ __forceinline__ float bf2f(u16 h){ return __uint_as_float(((u32)h)<<16); }

// e5m2 (bf8) = top byte of binary16. encode: f32->f16 RNE, then RNE to 8 bits.
__device__ __forceinline__ u8 f2bf8(float v){
  __half h = __float2half(v);
  u16 b = *(u16*)&h;
  return (u8)((b + 0x7Fu + ((b>>8)&1u)) >> 8);
}
__device__ __forceinline__ float bf82f(u32 byte){
  __half_raw r; r.x = (u16)(byte << 8);
  return __half2float(__half(r));
}

// jax.nn.gelu default (approximate=True, tanh form)
__device__ __forceinline__ float gelu_f(float x){
  float u = 0.7978845608028654f*(x + 0.044715f*x*x*x);
  float e = __expf(2.0f*u);
  return 0.5f*x*(2.0f - 2.0f/(e+1.0f));   // 0.5x(1+tanh(u)), overflow-safe
}

// ---------------------------------------------------------------------------
// Fused prologue: ONE dispatch for all mutually-independent prep work.
//   blocks [0,1536):   6 weight transposes (fp32 -> bf16 [N][Kpad])
//   [1536,1849):       out-init + bqk concat
//   [1849,6849):       LayerNorm x2 (zatt + xf[0:512])
//   [6849,9193):       edge histogram (deg zeroed by prior memset)
// ---------------------------------------------------------------------------
struct WttDesc { const float* W; u16* WT; int K, Nn, Kpad; };
struct WttPack { WttDesc d[6]; };

#define B_WTT  1536
#define B_PREP 313
#define B_LN2  5000
#define B_HIST 2344

__global__ __launch_bounds__(256) void misc_kernel(
    WttPack p,
    float* __restrict__ out, const float* __restrict__ beO, const float* __restrict__ bfO,
    float* __restrict__ bqk, const float* __restrict__ bq, const float* __restrict__ bk,
    float* __restrict__ bcat, const float* __restrict__ beI, const float* __restrict__ bfI,
    const float* __restrict__ x,
    const float* __restrict__ ga, const float* __restrict__ ba,
    const float* __restrict__ gm, const float* __restrict__ bm,
    u16* __restrict__ za, u16* __restrict__ xf,
    const int* __restrict__ ei, int* __restrict__ deg)
{
  __shared__ u16 tile[64][65];
  const int b = blockIdx.x;
  const int tid = threadIdx.x;
  if(b < B_WTT){
    const WttDesc dd = p.d[b >> 8];
    const int r8 = b & 255;
    const int k0 = (r8 & 15) << 6, n0 = (r8 >> 4) << 6;
    if(k0 >= dd.Kpad || n0 >= dd.Nn) return;
    const int tx = tid & 63, ty = tid >> 6;
#pragma unroll
    for(int i=0;i<16;i++){
      int r = (i<<2) + ty;
      int gk = k0 + r;
      float v = (gk < dd.K) ? dd.W[(size_t)gk*dd.Nn + n0 + tx] : 0.f;
      tile[r][tx] = f2bf(v);
    }
    __syncthreads();
#pragma unroll
    for(int i=0;i<16;i++){
      int r = (i<<2) + ty;
      dd.WT[(size_t)(n0 + r)*dd.Kpad + k0 + tx] = tile[tx][r];
    }
  } else if(b < B_WTT + B_PREP){
    int idx = (b - B_WTT)*256 + tid;
    if(idx < NN) out[idx] = beO[0];
    else if(idx < NN*4) out[idx] = bfO[(idx - NN) % 3];
    if(idx < 512) bqk[idx] = bq[idx];
    else if(idx < 1024) bqk[idx] = bk[idx-512];
    if(idx < 1024) bcat[idx] = beI[idx];
    else if(idx < 2048) bcat[idx] = bfI[idx-1024];
  } else if(b < B_WTT + B_PREP + B_LN2){
    int row = ((b - B_WTT - B_PREP)<<2) + (tid>>6);
    int lane = tid & 63;
    if(row >= NN) return;
    const float* xp = x + ((size_t)row<<9) + (lane<<3);
    f32x4 v0 = *(const f32x4*)xp;
    f32x4 v1 = *(const f32x4*)(xp+4);
    float vals[8] = {v0[0],v0[1],v0[2],v0[3],v1[0],v1[1],v1[2],v1[3]};
    float s=0.f, qs=0.f;
#pragma unroll
    for(int i=0;i<8;i++){ s += vals[i]; qs = fmaf(vals[i],vals[i],qs); }
#pragma unroll
    for(int o=1;o<64;o<<=1){ s += __shfl_xor(s,o); qs += __shfl_xor(qs,o); }
    float mean = s*(1.f/512.f);
    float var  = qs*(1.f/512.f) - mean*mean;
    float rstd = rsqrtf(var + 1e-5f);
    int c0 = lane<<3;
#pragma unroll
    for(int i=0;i<8;i++){
      float zn = (vals[i]-mean)*rstd;
      za[((size_t)row<<9)+c0+i] = f2bf(fmaf(zn, ga[c0+i], ba[c0+i]));
      xf[(size_t)row*576+c0+i]  = f2bf(fmaf(zn, gm[c0+i], bm[c0+i]));
    }
  } else {
    int e = (b - B_WTT - B_PREP - B_LN2)*256 + tid;
    if(e < EE) atomicAdd(&deg[ei[e]], 1);
  }
}

// ---------------------------------------------------------------------------
// GEMM: C[M,N] = A[M,K](bf16,row-stride lda) @ B^T[N,K](bf16) + bias.
// 128x128x64 tiles, MFMA 16x16x32, XOR-swizzled LDS, global_load_lds w=16,
// single-buffered (r5-verified; dbuf regressed twice). XCD-aware mapping.
// mode 0: QK projection: cols<512 -> q bf16 (stride 512); cols>=512 -> k bf8.
// mode 1: store gelu(v) bf16 (stride N). Energy half (tileN<1024) trims
//   K to 512 — its B columns 512..575 are WeI's zero pad.
// mode 2: MERGED hidden GEMM + fused residual/out-proj epilogue:
//   XCDs 0-3 energy head (B/bias/wout -> atomicAdd outp[row]);
//   XCDs 4-7 forces head (B2/bias2/wout2 3-ch -> atomicAdd outp2[row*3+c]).
// ---------------------------------------------------------------------------
__global__ __launch_bounds__(256) void gemm_bt(
    const u16* __restrict__ A, const u16* __restrict__ B,
    const float* __restrict__ bias, const u16* __restrict__ resid,
    u16* __restrict__ Cb, u8* __restrict__ k8,
    const float* __restrict__ wout, float* __restrict__ outp,
    const u16* __restrict__ B2, const float* __restrict__ bias2,
    const float* __restrict__ wout2, float* __restrict__ outp2,
    int M, int N, int K, int lda, int ldr, int mode)
{
  __shared__ u16 As[128*64];
  __shared__ u16 Bs[128*64];
  const int gx = gridDim.x;
  const int b  = blockIdx.y*gx + blockIdx.x;
  const int xcd = b & 7, loc = b >> 3;
  int tileM, tileN, half = 0;
  const u16* Ab = A; const u16* Bp = B; const float* bp = bias;
  if(mode < 2){
    tileM = ((loc/gx)*8 + xcd) << 7;
    tileN = (loc % gx) << 7;
  } else {
    half = xcd >> 2;
    const int mt = ((loc>>3)<<2) + (xcd & 3);
    tileM = mt << 7;
    tileN = (loc & 7) << 7;
    if(half){ Ab = A + 1024; Bp = B2; bp = bias2; }
  }
  if(tileM >= M) return;
  int keff = K;
  if(mode == 1 && tileN < 1024) keff = 512;   // energy in-proj: skip zero pad
  const int tid  = threadIdx.x;
  const int wave = tid>>6, lane = tid&63;
  const int quad = lane>>4, l15 = lane&15;
  const int mhalf = (wave>>1)<<6, nhalf = (wave&1)<<6;
  f32x4 acc[4][4] = {};

  for(int k0=0; k0<keff; k0+=64){
#pragma unroll
    for(int j=0;j<4;j++){
      const int c   = (((wave<<2)+j)<<6) + lane;   // LDS chunk this lane fills
      const int row = c>>3;
      const int cc  = (c&7) ^ (row&7);             // logical k-chunk landing here
      int gr = tileM + row; gr = (gr < M) ? gr : (M-1);
      const u16* gp = Ab + (size_t)gr*lda + (size_t)(k0 + (cc<<3));
      __builtin_amdgcn_global_load_lds(
        (const __attribute__((address_space(1))) u32*)gp,
        (__attribute__((address_space(3))) u32*)(&As[((wave<<2)+j)<<9]),
        16, 0, 0);
    }
#pragma unroll
    for(int j=0;j<4;j++){
      const int c   = (((wave<<2)+j)<<6) + lane;
      const int row = c>>3;
      const int cc  = (c&7) ^ (row&7);
      const u16* gp = Bp + (size_t)(tileN + row)*K + (size_t)(k0 + (cc<<3));
      __builtin_amdgcn_global_load_lds(
        (const __attribute__((address_space(1))) u32*)gp,
        (__attribute__((address_space(3))) u32*)(&Bs[((wave<<2)+j)<<9]),
        16, 0, 0);
    }
    __syncthreads();
#pragma unroll
    for(int ks=0;ks<2;ks++){
      const int ccol = (ks<<2) + quad;             // logical 16B k-chunk index
      u32x4 af[4], bfr[4];
#pragma unroll
      for(int mi=0;mi<4;mi++){
        const int row = mhalf + (mi<<4) + l15;
        af[mi] = *(const u32x4*)&As[((row<<3) + (ccol ^ (row&7)))<<3];
      }
#pragma unroll
      for(int ni=0;ni<4;ni++){
        const int row = nhalf + (ni<<4) + l15;
        bfr[ni] = *(const u32x4*)&Bs[((row<<3) + (ccol ^ (row&7)))<<3];
      }
#pragma unroll
      for(int mi=0;mi<4;mi++)
#pragma unroll
        for(int ni=0;ni<4;ni++)
          asm("v_mfma_f32_16x16x32_bf16 %0, %1, %2, %0"
              : "+v"(acc[mi][ni]) : "v"(af[mi]), "v"(bfr[ni]));
    }
    __syncthreads();
  }

  if(mode == 0){
#pragma unroll
    for(int mi=0;mi<4;mi++){
#pragma unroll
      for(int reg=0;reg<4;reg++){
        const int gr = tileM + mhalf + (mi<<4) + (quad<<2) + reg;
        if(gr < M){
#pragma unroll
          for(int ni=0;ni<4;ni++){
            const int gc = tileN + nhalf + (ni<<4) + l15;
            float v = acc[mi][ni][reg] + bp[gc];
            if(gc < 512) Cb[(size_t)gr*512 + gc] = f2bf(v);       // q bf16
            else         k8[(size_t)gr*512 + gc - 512] = f2bf8(v); // k bf8
          }
        }
      }
    }
  } else if(mode == 1){
#pragma unroll
    for(int mi=0;mi<4;mi++){
#pragma unroll
      for(int reg=0;reg<4;reg++){
        const int gr = tileM + mhalf + (mi<<4) + (quad<<2) + reg;
        if(gr < M){
#pragma unroll
          for(int ni=0;ni<4;ni++){
            const int gc = tileN + nhalf + (ni<<4) + l15;
            Cb[(size_t)gr*N + gc] = f2bf(gelu_f(acc[mi][ni][reg] + bp[gc]));
          }
        }
      }
    }
  } else if(!half){
    // energy head: v = resid + gelu(v); outp[row] += sum_col v*wout[col]
    float wv[4], bv[4];
#pragma unroll
    for(int ni=0;ni<4;ni++){
      int gc = tileN + nhalf + (ni<<4) + l15;
      wv[ni] = wout[gc]; bv[ni] = bp[gc];
    }
#pragma unroll
    for(int mi=0;mi<4;mi++){
#pragma unroll
      for(int reg=0;reg<4;reg++){
        const int gr = tileM + mhalf + (mi<<4) + (quad<<2) + reg;
        if(gr < M){
          float vs = 0.f;
#pragma unroll
          for(int ni=0;ni<4;ni++){
            const int gc = tileN + nhalf + (ni<<4) + l15;
            float v = gelu_f(acc[mi][ni][reg] + bv[ni])
                    + bf2f(resid[(size_t)gr*ldr + gc]);
            vs = fmaf(v, wv[ni], vs);
          }
          vs += __shfl_xor(vs,1); vs += __shfl_xor(vs,2);
          vs += __shfl_xor(vs,4); vs += __shfl_xor(vs,8);
          if(l15 == 0) atomicAdd(&outp[gr], vs);
        }
      }
    }
  } else {
    // forces head: 3 channels; resid offset +1024 (h1cat forces half)
    float wv0[4], wv1[4], wv2[4], bv[4];
#pragma unroll
    for(int ni=0;ni<4;ni++){
      int gc = tileN + nhalf + (ni<<4) + l15;
      wv0[ni] = wout2[gc*3+0]; wv1[ni] = wout2[gc*3+1]; wv2[ni] = wout2[gc*3+2];
      bv[ni] = bp[gc];
    }
#pragma unroll
    for(int mi=0;mi<4;mi++){
#pragma unroll
      for(int reg=0;reg<4;reg++){
        const int gr = tileM + mhalf + (mi<<4) + (quad<<2) + reg;
        if(gr < M){
          float s0=0.f, s1=0.f, s2=0.f;
#pragma unroll
          for(int ni=0;ni<4;ni++){
            const int gc = tileN + nhalf + (ni<<4) + l15;
            float v = gelu_f(acc[mi][ni][reg] + bv[ni])
                    + bf2f(resid[(size_t)gr*ldr + 1024 + gc]);
            s0 = fmaf(v, wv0[ni], s0);
            s1 = fmaf(v, wv1[ni], s1);
            s2 = fmaf(v, wv2[ni], s2);
          }
          s0 += __shfl_xor(s0,1); s0 += __shfl_xor(s0,2); s0 += __shfl_xor(s0,4); s0 += __shfl_xor(s0,8);
          s1 += __shfl_xor(s1,1); s1 += __shfl_xor(s1,2); s1 += __shfl_xor(s1,4); s1 += __shfl_xor(s1,8);
          s2 += __shfl_xor(s2,1); s2 += __shfl_xor(s2,2); s2 += __shfl_xor(s2,4); s2 += __shfl_xor(s2,8);
          if(l15 == 0){
            atomicAdd(&outp2[(size_t)gr*3+0], s0);
            atomicAdd(&outp2[(size_t)gr*3+1], s1);
            atomicAdd(&outp2[(size_t)gr*3+2], s2);
          }
        }
      }
    }
  }
}

// single-block exclusive scan, shuffle-based (2 barriers per 1024 chunk)
__global__ __launch_bounds__(1024) void scan_kernel(
    const int* __restrict__ deg, int* __restrict__ rowptr,
    int* __restrict__ cursor, int N)
{
  __shared__ int wsum[16];
  __shared__ int carry_s;
  const int tid = threadIdx.x, lane = tid & 63, wid = tid >> 6;
  if(tid == 0) carry_s = 0;
  __syncthreads();
  for(int base = 0; base < N; base += 1024){
    int idx = base + tid;
    int v = (idx < N) ? deg[idx] : 0;
    int s = v;
#pragma unroll
    for(int o=1;o<64;o<<=1){ int t = __shfl_up(s,o); if(lane>=o) s += t; }
    if(lane==63) wsum[wid] = s;
    __syncthreads();
    if(wid==0 && lane<16){
      int ws = wsum[lane];
      int t = ws;
#pragma unroll
      for(int o=1;o<16;o<<=1){ int u = __shfl_up(t,o); if(lane>=o) t += u; }
      wsum[lane] = t - ws;
    }
    __syncthreads();
    int ex = s - v + wsum[wid] + carry_s;
    if(idx < N){ rowptr[idx] = ex; cursor[idx] = ex; }
    __syncthreads();
    if(tid == 1023) carry_s += wsum[15] + s;
  }
  __syncthreads();
  if(tid == 0) rowptr[N] = carry_s;
}

__global__ __launch_bounds__(256) void scatter_kernel(
    const int* __restrict__ ei, const float* __restrict__ ab,
    int* __restrict__ cursor, int* __restrict__ cols,
    float* __restrict__ abs_, int E)
{
  int e = blockIdx.x*256 + threadIdx.x;
  if(e >= E) return;
  int r = ei[e];
  int p = atomicAdd(&cursor[r], 1);
  cols[p] = ei[EE + e];
  abs_[p] = ab[e];
}

// ---------------------------------------------------------------------------
// Per-node attention: one wave per node. q-row (bf16) in registers; gather
// sorted k-rows (bf8, half the bytes); softmax without max-subtraction;
// denom & weighted pos in registers (no atomics); att-pos -> xf[512:536].
// 8 edges in flight per iteration. No LDS -> full 8-block/CU occupancy.
// ---------------------------------------------------------------------------
__global__ __launch_bounds__(256) void node_att_kernel(
    const u16* __restrict__ qd, const u8* __restrict__ k8,
    const int* __restrict__ rowptr, const int* __restrict__ cols,
    const float* __restrict__ abs_, const float* __restrict__ pos,
    u16* __restrict__ xf, int N)
{
  const int node = (blockIdx.x<<2) + (threadIdx.x>>6);
  const int lane = threadIdx.x & 63;
  if(node >= N) return;
  const int h = lane>>3, sub = lane&7;
  const u32x4 qv = *(const u32x4*)(qd + ((size_t)node<<9) + (lane<<3));
  float qf[8];
#pragma unroll
  for(int i=0;i<4;i++){
    qf[2*i]   = __uint_as_float(qv[i]<<16);
    qf[2*i+1] = __uint_as_float(qv[i]&0xffff0000u);
  }
  const float posn = (sub<3) ? pos[node*3 + sub] : 0.f;
  const int j1 = rowptr[node+1];
  float den = 0.f, nm = 0.f;

  int j = rowptr[node];
  for(; j+7 < j1; j += 8){
    int c[8]; float abv[8], pv[8]; u32x2 kw[8];
#pragma unroll
    for(int t=0;t<8;t++){ c[t] = cols[j+t]; abv[t] = abs_[j+t]; }
#pragma unroll
    for(int t=0;t<8;t++){
      kw[t] = *(const u32x2*)(k8 + ((size_t)c[t]<<9) + (lane<<3));
      pv[t] = (sub<3) ? pos[c[t]*3+sub] : 0.f;
    }
#pragma unroll
    for(int t=0;t<8;t++){
      float s = 0.f;
#pragma unroll
      for(int i=0;i<8;i++){
        u32 byte = (kw[t][i>>2] >> ((i&3)<<3)) & 0xFFu;
        s = fmaf(qf[i], bf82f(byte), s);
      }
      s += __shfl_xor(s,1); s += __shfl_xor(s,2); s += __shfl_xor(s,4);
      float p = __expf(fmaf(s, 0.125f, abv[t]));
      den += p;
      nm = fmaf(p, pv[t], nm);
    }
  }
  for(; j < j1; j++){
    int c0 = cols[j];
    u32x2 kw0 = *(const u32x2*)(k8 + ((size_t)c0<<9) + (lane<<3));
    float pv0 = (sub<3) ? pos[c0*3+sub] : 0.f;
    float s0=0.f;
#pragma unroll
    for(int i=0;i<8;i++){
      u32 byte = (kw0[i>>2] >> ((i&3)<<3)) & 0xFFu;
      s0 = fmaf(qf[i], bf82f(byte), s0);
    }
    s0 += __shfl_xor(s0,1); s0 += __shfl_xor(s0,2); s0 += __shfl_xor(s0,4);
    float p0 = __expf(fmaf(s0, 0.125f, abs_[j]));
    den += p0;
    nm = fmaf(p0, pv0, nm);
  }

  u16* xp = xf + (size_t)node*576;
  if(sub < 3){
    float a = (den > 0.f) ? nm/den : 0.f;
    xp[512 + h*3 + sub] = f2bf(a - posn);
  } else {
    xp[536 + h*5 + (sub-3)] = 0;   // pad cols 536..575
  }
}

// ---------------------------------------------------------------------------
extern "C" void kernel_launch(void* const* d_in, const int* in_sizes, int n_in,
                              void* d_out, int out_size, void* d_ws, size_t ws_size,
                              hipStream_t stream)
{
  (void)in_sizes; (void)n_in; (void)out_size; (void)ws_size;
  const float* x    = (const float*)d_in[0];
  const int*   ei   = (const int*)d_in[1];
  const float* ab   = (const float*)d_in[2];
  const float* pos  = (const float*)d_in[3];
  const float* g_att= (const float*)d_in[5];
  const float* b_att= (const float*)d_in[6];
  const float* g_mlp= (const float*)d_in[7];
  const float* b_mlp= (const float*)d_in[8];
  const float* Wq   = (const float*)d_in[9];  const float* bq  = (const float*)d_in[10];
  const float* Wk   = (const float*)d_in[11]; const float* bk  = (const float*)d_in[12];
  const float* WeI  = (const float*)d_in[13]; const float* beI = (const float*)d_in[14];
  const float* WeH  = (const float*)d_in[15]; const float* beH = (const float*)d_in[16];
  const float* WeO  = (const float*)d_in[17]; const float* beO = (const float*)d_in[18];
  const float* WfI  = (const float*)d_in[19]; const float* bfI = (const float*)d_in[20];
  const float* WfH  = (const float*)d_in[21]; const float* bfH = (const float*)d_in[22];
  const float* WfO  = (const float*)d_in[23]; const float* bfO = (const float*)d_in[24];

  char* w = (char*)d_ws;
  size_t off = 0;
  auto alloc = [&](size_t bytes) -> void* {
    void* p = w + off; off += (bytes + 255) & ~(size_t)255; return p;
  };
  u16* zatt  = (u16*)alloc((size_t)NN*512*2);
  u16* qd    = (u16*)alloc((size_t)NN*512*2);    // q bf16
  u8*  k8    = (u8*) alloc((size_t)NN*512);      // k bf8 (e5m2)
  u16* xf    = (u16*)alloc((size_t)NN*576*2);    // [z_mlp(512)|att(24)|0(40)]
  u16* h1cat = (u16*)alloc((size_t)NN*2048*2);   // [h1_energy(1024)|h1_forces(1024)]
  u16* wqkT  = (u16*)alloc((size_t)1024*512*2);
  u16* wInT  = (u16*)alloc((size_t)2048*576*2);  // [WeI_T pad576 | WfI_T]
  u16* weHT  = (u16*)alloc((size_t)1024*1024*2);
  u16* wfHT  = (u16*)alloc((size_t)1024*1024*2);
  float* bqk    = (float*)alloc((size_t)1024*4);
  float* bcat   = (float*)alloc((size_t)2048*4); // [beI|bfI]
  int*   deg    = (int*)alloc((size_t)NN*4);
  int*   rowptr = (int*)alloc((size_t)(NN+1)*4);
  int*   cursor = (int*)alloc((size_t)NN*4);
  int*   cols   = (int*)alloc((size_t)EE*4);
  float* absrt  = (float*)alloc((size_t)EE*4);

  hipMemsetAsync(deg, 0, (size_t)NN*4, stream);

  // fused prologue: 6 weight transposes + out/bias init + LN x2 + histogram
  WttPack pk;
  pk.d[0] = { Wq,  wqkT,            512,  512,  512 };
  pk.d[1] = { Wk,  wqkT + 512*512,  512,  512,  512 };
  pk.d[2] = { WeI, wInT,            512,  1024, 576 };
  pk.d[3] = { WfI, wInT + 1024*576, 536,  1024, 576 };
  pk.d[4] = { WeH, weHT,            1024, 1024, 1024 };
  pk.d[5] = { WfH, wfHT,            1024, 1024, 1024 };
  misc_kernel<<<dim3(B_WTT+B_PREP+B_LN2+B_HIST),256,0,stream>>>(
      pk, (float*)d_out, beO, bfO, bqk, bq, bk, bcat, beI, bfI,
      x, g_att, b_att, g_mlp, b_mlp, zatt, xf, ei, deg);

  scan_kernel   <<<1,1024,0,stream>>>(deg, rowptr, cursor, NN);
  scatter_kernel<<<dim3((EE+255)/256),256,0,stream>>>(ei, ab, cursor, cols, absrt, EE);

  const int MT = 160;  // 157 M-tiles padded to multiple of 8 (XCD stripes)

  // fused Q+K projection: q -> qd (bf16), k -> k8 (bf8)
  gemm_bt<<<dim3(8, MT),256,0,stream>>>(zatt, wqkT, bqk, nullptr, qd, k8,
                                        nullptr, nullptr,
                                        nullptr, nullptr, nullptr, nullptr,
                                        NN, 1024, 512, 512, 0, 0);

  node_att_kernel<<<dim3((NN+3)/4),256,0,stream>>>(qd, k8, rowptr, cols, absrt, pos, xf, NN);

  // fused in-projections: h1cat = gelu(xf @ [WeI(pad)|WfI] + bcat), N=2048
  // (energy tiles trim K to 512 inside the kernel — WeI pad is zero)
  gemm_bt<<<dim3(16, MT),256,0,stream>>>(xf, wInT, bcat, nullptr, h1cat, nullptr,
                                         nullptr, nullptr,
                                         nullptr, nullptr, nullptr, nullptr,
                                         NN, 2048, 576, 576, 0, 1);

  // MERGED hidden GEMM: XCDs 0-3 energy, XCDs 4-7 forces. One dispatch.
  gemm_bt<<<dim3(8, 2*MT),256,0,stream>>>(h1cat, weHT, beH, h1cat, nullptr, nullptr,
                                          WeO, (float*)d_out,
                                          wfHT, bfH, WfO, (float*)d_out + NN,
                                          NN, 1024, 1024, 2048, 2048, 2);
}